// Round 8
// baseline (139.111 us; speedup 1.0000x reference)
//
#include <hip/hip_runtime.h>

// B=8, H=W=128, Cin=128, Cout=256, 3x3 stride2 pad1 -> OH=OW=64.
// Implicit GEMM: M=32768, N=256, K=1152 (9 taps x 128).
// d_out (f32): out_feats[32768*256] | out_coords[32768*3] | alpha[1]
// R8: 64x128 tiles (1024 blocks, 3 blocks/CU via 48KB dbuf LDS) + XCD-swizzled
//     block mapping (each XCD owns one batch image -> A is L2-resident).

#define OUT_FEATS_ELEMS (32768 * 256)
#define OUT_COORDS_OFF  OUT_FEATS_ELEMS
#define ALPHA_OFF       (OUT_FEATS_ELEMS + 32768 * 3)

typedef float v16f __attribute__((ext_vector_type(16)));

__device__ __forceinline__ unsigned pk4fp8(float a, float b, float c, float d) {
    unsigned u = 0;
    u = __builtin_amdgcn_cvt_pk_fp8_f32(a, b, u, false);  // bytes 0,1
    u = __builtin_amdgcn_cvt_pk_fp8_f32(c, d, u, true);   // bytes 2,3
    return u;
}

#define GLOAD_LDS16(SRC, DST)                                                  \
    __builtin_amdgcn_global_load_lds(                                          \
        (const __attribute__((address_space(1))) void*)(SRC),                  \
        (__attribute__((address_space(3))) void*)(DST), 16, 0, 0)

// ---- merged prepass: feats fp32->fp8 (blocks 0..8191);
//      weight -> pre-swizzled fp8 images + coords + alpha (blocks 8192..8335) ----
// Image[t=nb*9+tap][row 0..127][ch 0..7] (16B chunks):
//   fp8 of w[k = tap*128 + (ch^(row&7))*16 + j][n = nb*128 + row], j=0..15
__global__ void prep_kernel(const float* __restrict__ feats, const float* __restrict__ w,
                            const float* __restrict__ alpha,
                            unsigned char* __restrict__ F8, unsigned char* __restrict__ Bw,
                            float* __restrict__ out) {
    int bid = blockIdx.x;
    if (bid < 8192) {                             // feats: 2097152 threads x 8 elems
        int i = bid * 256 + threadIdx.x;
        const float4* f = (const float4*)feats;
        float4 a = f[2 * i];
        float4 b = f[2 * i + 1];
        uint2 r;
        r.x = pk4fp8(a.x, a.y, a.z, a.w);
        r.y = pk4fp8(b.x, b.y, b.z, b.w);
        ((uint2*)F8)[i] = r;
        return;
    }
    int cid = (bid - 8192) * 256 + threadIdx.x;   // 0..36863
    if (cid < 32768) {                            // coords
        int b = cid >> 12, iy = (cid >> 6) & 63, ix = cid & 63;
        float* c = out + OUT_COORDS_OFF + (size_t)cid * 3;
        c[0] = (float)b; c[1] = (float)iy; c[2] = (float)ix;
        if (cid == 0) out[ALPHA_OFF] = alpha[0];
    }
    if (cid < 18432) {                            // 18 images x 128 rows x 8 chunks
        int ch  = cid & 7;
        int row = (cid >> 3) & 127;
        int t   = cid >> 10;                      // 0..17 = nb*9 + tap
        int nb  = (t >= 9) ? 1 : 0;
        int tap = t - 9 * nb;
        int chp = ch ^ (row & 7);
        int n   = (nb << 7) + row;
        int kb  = (tap << 7) + (chp << 4);
        unsigned u[4];
#pragma unroll
        for (int q = 0; q < 4; ++q) {
            float f0 = w[(size_t)(kb + 4 * q + 0) * 256 + n];
            float f1 = w[(size_t)(kb + 4 * q + 1) * 256 + n];
            float f2 = w[(size_t)(kb + 4 * q + 2) * 256 + n];
            float f3 = w[(size_t)(kb + 4 * q + 3) * 256 + n];
            u[q] = pk4fp8(f0, f1, f2, f3);
        }
        uint4 r; r.x = u[0]; r.y = u[1]; r.z = u[2]; r.w = u[3];
        *(uint4*)(Bw + (size_t)cid * 16) = r;
    }
}

// ---- coords for fallback path ----
__global__ void coords_alpha_kernel(float* __restrict__ out, const float* __restrict__ alpha) {
    int i = blockIdx.x * 256 + threadIdx.x;
    int b = i >> 12, iy = (i >> 6) & 63, ix = i & 63;
    float* c = out + OUT_COORDS_OFF + (size_t)i * 3;
    c[0] = (float)b; c[1] = (float)iy; c[2] = (float)ix;
    if (i == 0) out[ALPHA_OFF] = alpha[0];
}

// ---- main implicit GEMM: 64x128 tile (one output row), BK=128/tap, 32x32x16 fp8 MFMA,
//      double-buffered LDS (48KB), 3 blocks/CU, XCD-swizzled mapping ----
__global__ __launch_bounds__(256, 3) void gemm_conv_kernel(
    const unsigned char* __restrict__ F8,    // fp8 feats [B*128*128][128]
    const unsigned char* __restrict__ Bw,    // pre-swizzled fp8 B images (18 x 16KB)
    float* __restrict__ out)                 // [32768][256]
{
    __shared__ unsigned char At[2][64 * 128];   // 8KB per buffer, chunk-swizzled
    __shared__ unsigned char Bs[2][128 * 128];  // 16KB per buffer

    const int tid  = threadIdx.x;
    const int bid  = blockIdx.x;             // 0..1023
    const int xcd  = bid & 7;                // round-robin XCD assignment (heuristic)
    const int s    = bid >> 3;               // 0..127
    const int nb   = s & 1;                  // nb-pair: bids differ by 8 -> same XCD
    const int my   = (xcd << 6) + (s >> 1);  // 0..511 ; bb = my>>6 = xcd (one batch/XCD)
    const int n0   = nb << 7;
    const int m0   = my << 6;
    const int bb   = my >> 6;
    const int iy   = my & 63;                // this block's single output row

    const int lane = tid & 63, wave = tid >> 6;
    const int wm   = (wave & 1) << 5;        // wave m-offset (0/32)
    const int wn   = (wave >> 1) << 6;       // wave n-offset (0/64)
    const int l31  = lane & 31;
    const int hh   = lane >> 5;              // k-half select
    const int xorl = l31 & 7;

    // staging: region covers 8 rows x 128B (64 lanes x 16B); lane -> srow=lane>>3, chunk=lane&7
    const int srow = lane >> 3;              // 0..7
    const int chp  = (lane & 7) ^ srow;      // swizzled source chunk (row&7 == srow)
    const long rowA0 = (long)bb << 14;
    const unsigned char* bimg = Bw + ((size_t)(nb * 9) << 14) + ((size_t)wave << 12) + ((size_t)lane << 4);

    v16f acc[2];
    acc[0] = (v16f)(0.0f); acc[1] = (v16f)(0.0f);

    // stage tap t into buffer b: A regions wave*2+it (it 0..1), B regions wave*4+it (it 0..3)
    auto stage = [&](int tap, int b) {
        const int dy = tap / 3 - 1;
        const int dx = tap % 3 - 1;
        unsigned char* adst = At[b] + (wave << 11);
        unsigned char* bdst = Bs[b] + (wave << 12);
#pragma unroll
        for (int it = 0; it < 4; ++it)
            GLOAD_LDS16(bimg + ((size_t)tap << 14) + (it << 10), bdst + (it << 10));
        const int ny = (iy << 1) + dy;       // uniform for whole block
        const bool vy = (unsigned)ny < 128u;
        const long prow = rowA0 + ((long)ny << 7);
#pragma unroll
        for (int it = 0; it < 2; ++it) {
            const int ix = (((wave << 1) + it) << 3) + srow;  // 0..63 (m-local row)
            const int nx = (ix << 1) + dx;
            if (vy & ((unsigned)nx < 128u)) {
                GLOAD_LDS16(F8 + ((prow + nx) << 7) + (chp << 4), adst + (it << 10));
            } else {
                uint4 z; z.x = 0u; z.y = 0u; z.z = 0u; z.w = 0u;
                *(uint4*)(At[b] + (((wave << 1) + it) << 10) + (lane << 4)) = z;
            }
        }
    };

    stage(0, 0);                              // prefetch tap 0

    for (int tap = 0; tap < 9; ++tap) {
        const int b = tap & 1;
        // barrier drains this wave's DMA for tap (issued one compute-phase ago)
        // and closes readers of buffer b (tap-2's compute).
        __syncthreads();
        if (tap < 8) stage(tap + 1, b ^ 1);   // issue next tap's DMA before computing

#pragma unroll
        for (int seg = 0; seg < 8; ++seg) {   // K=128 -> 8 x (32x32x16)
            const int q = seg ^ xorl;         // phys chunk (row&7 == l31&7)
            long long a  = *(const long long*)(At[b] + ((wm + l31) << 7) + (q << 4) + (hh << 3));
            long long b0 = *(const long long*)(Bs[b] + ((wn + l31) << 7) + (q << 4) + (hh << 3));
            long long b1 = *(const long long*)(Bs[b] + ((wn + 32 + l31) << 7) + (q << 4) + (hh << 3));
            acc[0] = __builtin_amdgcn_mfma_f32_32x32x16_fp8_fp8(a, b0, acc[0], 0, 0, 0);
            acc[1] = __builtin_amdgcn_mfma_f32_32x32x16_fp8_fp8(a, b1, acc[1], 0, 0, 0);
        }
    }

    // epilogue: 32x32 D layout col=lane&31, row=(reg&3)+8*(reg>>2)+4*(lane>>5)  [m74/m101]
#pragma unroll
    for (int j = 0; j < 2; j++) {
        const int gcol = n0 + wn + (j << 5) + l31;
#pragma unroll
        for (int r = 0; r < 16; ++r) {
            const int grow = m0 + wm + (r & 3) + ((r >> 2) << 3) + (hh << 2);
            out[(size_t)grow * 256 + gcol] = acc[j][r];
        }
    }
}

// ---- fallback: direct fp32 conv ----
__global__ void naive_conv_kernel(const float* __restrict__ feats,
                                  const float* __restrict__ w,
                                  float* __restrict__ out) {
    int m = blockIdx.x;
    int n = threadIdx.x;
    int bb = m >> 12, iy = (m >> 6) & 63, ix = m & 63;
    float acc = 0.f;
    for (int tap = 0; tap < 9; ++tap) {
        int ny = 2 * iy + tap / 3 - 1;
        int nx = 2 * ix + tap % 3 - 1;
        if ((unsigned)ny < 128u && (unsigned)nx < 128u) {
            const float* fr = feats + ((size_t)((bb << 14) + (ny << 7) + nx) << 7);
            const float* wr = w + tap * 32768 + n;
            for (int c = 0; c < 128; ++c) acc += fr[c] * wr[c * 256];
        }
    }
    out[(size_t)m * 256 + n] = acc;
}

extern "C" void kernel_launch(void* const* d_in, const int* in_sizes, int n_in,
                              void* d_out, int out_size, void* d_ws, size_t ws_size,
                              hipStream_t stream) {
    const float* feats  = (const float*)d_in[0];
    const float* weight = (const float*)d_in[1];
    const float* alpha  = (const float*)d_in[2];
    float* out = (float*)d_out;

    const size_t NEED = (size_t)16777216 + (size_t)18 * 16384; // 17,072,128 B
    if (ws_size >= NEED) {
        unsigned char* F8 = (unsigned char*)d_ws;
        unsigned char* Bw = F8 + 16777216;
        prep_kernel<<<8336, 256, 0, stream>>>(feats, weight, alpha, F8, Bw, out);
        gemm_conv_kernel<<<1024, 256, 0, stream>>>(F8, Bw, out);
    } else {
        coords_alpha_kernel<<<128, 256, 0, stream>>>(out, alpha);
        naive_conv_kernel<<<32768, 256, 0, stream>>>(feats, weight, out);
    }
}